// Round 5
// baseline (677.547 us; speedup 1.0000x reference)
//
#include <hip/hip_runtime.h>
#include <stdint.h>

#define DEV __device__ __forceinline__

typedef unsigned short u16;
typedef short s16x8 __attribute__((ext_vector_type(8)));
typedef u16 u16x4 __attribute__((ext_vector_type(4)));
typedef float f32x4 __attribute__((ext_vector_type(4)));

constexpr int Bc = 4, Tc = 2048, Ec = 1024, Hc = 16, DHc = 64, FFc = 4096;

DEV u16 f2bf(float f) {
    union { float f; uint32_t u; } v; v.f = f;
    uint32_t r = v.u + 0x7fffu + ((v.u >> 16) & 1u);
    return (u16)(r >> 16);
}
DEV float bf2f(u16 u) {
    union { uint32_t u; float f; } v; v.u = ((uint32_t)u) << 16;
    return v.f;
}
DEV uint32_t cvtpk_bf16(float lo, float hi) {
    uint32_t r;
    asm("v_cvt_pk_bf16_f32 %0, %1, %2" : "=v"(r) : "v"(lo), "v"(hi));
    return r;
}

// async global->LDS, 16B per lane, dest = wave-uniform base + lane*16
DEV void gload16(const void* g, void* l) {
    __builtin_amdgcn_global_load_lds((const __attribute__((address_space(1))) void*)g,
                                     (__attribute__((address_space(3))) void*)l, 16, 0, 0);
}

// ---------------- transpose + convert:  in [R][C] (f32 or bf16) -> out bf16 [C][R]
template <typename TIN>
__global__ __launch_bounds__(256) void transpose_conv(const TIN* __restrict__ in,
                                                      u16* __restrict__ out, int R, int C) {
    __shared__ float tile[32][33];
    int bz = blockIdx.z;
    in  += (size_t)bz * R * C;
    out += (size_t)bz * R * C;
    int c0 = blockIdx.x * 32, r0 = blockIdx.y * 32;
    int tx = threadIdx.x, ty = threadIdx.y;  // 32 x 8
#pragma unroll
    for (int i = 0; i < 4; i++) {
        int r = ty + 8 * i;
        float v;
        if constexpr (sizeof(TIN) == 4) v = ((const float*)in)[(size_t)(r0 + r) * C + c0 + tx];
        else                            v = bf2f(((const u16*)in)[(size_t)(r0 + r) * C + c0 + tx]);
        tile[r][tx] = v;
    }
    __syncthreads();
#pragma unroll
    for (int i = 0; i < 4; i++) {
        int c = ty + 8 * i;
        out[(size_t)(c0 + c) * R + r0 + tx] = f2bf(tile[tx][c]);
    }
}

// ---------------- LayerNorm (row of 1024 f32) -> bf16
__global__ __launch_bounds__(256) void ln_kernel(const float* __restrict__ x, const float* __restrict__ g,
                                                 const float* __restrict__ b, u16* __restrict__ out) {
    int row = blockIdx.x;
    const float4* xr = (const float4*)(x + (size_t)row * Ec);
    int t = threadIdx.x;
    float4 v = xr[t];
    float s = v.x + v.y + v.z + v.w;
    float ss = v.x * v.x + v.y * v.y + v.z * v.z + v.w * v.w;
#pragma unroll
    for (int off = 32; off > 0; off >>= 1) { s += __shfl_xor(s, off); ss += __shfl_xor(ss, off); }
    __shared__ float red[8];
    int wid = t >> 6;
    if ((t & 63) == 0) { red[wid] = s; red[4 + wid] = ss; }
    __syncthreads();
    s = red[0] + red[1] + red[2] + red[3];
    ss = red[4] + red[5] + red[6] + red[7];
    float mu = s * (1.f / Ec);
    float rs = rsqrtf(ss * (1.f / Ec) - mu * mu + 1e-5f);
    float4 gv = ((const float4*)g)[t], bv = ((const float4*)b)[t];
    u16x4 o;
    o[0] = f2bf((v.x - mu) * rs * gv.x + bv.x);
    o[1] = f2bf((v.y - mu) * rs * gv.y + bv.y);
    o[2] = f2bf((v.z - mu) * rs * gv.z + bv.z);
    o[3] = f2bf((v.w - mu) * rs * gv.w + bv.w);
    *(u16x4*)(out + (size_t)row * Ec + t * 4) = o;
}

// ---------------- GEMM: C[M,N] = A[M,K](bf16) * Bt[N,K](bf16)^T, m97 structure
// XCD-chunk swizzled block mapping (nwg % 8 == 0 for all our grids).
// MODE 0: qkv split-store bf16: Q,K,V -> [B,H,T,64] (coalesced)
// MODE 1: bf16 out = relu(acc + bias)
// MODE 2: f32 out = acc + bias + res
template <int MODE>
__global__ __launch_bounds__(256) void gemm_kernel(const u16* __restrict__ A, const u16* __restrict__ Bt,
                                                   int K, int N,
                                                   u16* __restrict__ o0, u16* __restrict__ o1, u16* __restrict__ o2,
                                                   float* __restrict__ of, const float* __restrict__ bias,
                                                   const float* __restrict__ res) {
    __shared__ u16 As[128 * 32];
    __shared__ u16 Bs[128 * 32];
    int lin = blockIdx.y * gridDim.x + blockIdx.x;
    int cpx = (gridDim.x * gridDim.y) >> 3;
    int swz = (lin & 7) * cpx + (lin >> 3);
    int tm = (swz / gridDim.x) * 128, tn = (swz % gridDim.x) * 128;
    int tid = threadIdx.x;
    int w = tid >> 6, l = tid & 63;
    int wm = w >> 1, wn = w & 1;
    int q16 = l & 15, g = l >> 4;

    f32x4 acc[4][4];
#pragma unroll
    for (int i = 0; i < 4; i++)
#pragma unroll
        for (int j = 0; j < 4; j++) acc[i][j] = {0.f, 0.f, 0.f, 0.f};

    const u16* Aw0 = A + (size_t)(tm + w * 32 + (l >> 2)) * K + (l & 3) * 8;
    const u16* Aw1 = Aw0 + (size_t)16 * K;
    const u16* Bw0 = Bt + (size_t)(tn + w * 32 + (l >> 2)) * K + (l & 3) * 8;
    const u16* Bw1 = Bw0 + (size_t)16 * K;
    u16* Asw = As + (w * 32) * 32;
    u16* Bsw = Bs + (w * 32) * 32;

    for (int k0 = 0; k0 < K; k0 += 32) {
        gload16(Aw0 + k0, Asw);
        gload16(Aw1 + k0, Asw + 16 * 32);
        gload16(Bw0 + k0, Bsw);
        gload16(Bw1 + k0, Bsw + 16 * 32);
        asm volatile("s_waitcnt vmcnt(0)" ::: "memory");
        __syncthreads();
        s16x8 af[4], bfr[4];
#pragma unroll
        for (int i = 0; i < 4; i++) {
            af[i]  = *(const s16x8*)(As + (wm * 64 + i * 16 + q16) * 32 + g * 8);
            bfr[i] = *(const s16x8*)(Bs + (wn * 64 + i * 16 + q16) * 32 + g * 8);
        }
#pragma unroll
        for (int i = 0; i < 4; i++)
#pragma unroll
            for (int j = 0; j < 4; j++)
                acc[i][j] = __builtin_amdgcn_mfma_f32_16x16x32_bf16(af[i], bfr[j], acc[i][j], 0, 0, 0);
        __syncthreads();
    }

#pragma unroll
    for (int i = 0; i < 4; i++) {
        int m0 = tm + wm * 64 + i * 16 + g * 4;
#pragma unroll
        for (int j = 0; j < 4; j++) {
            int n = tn + wn * 64 + j * 16 + q16;
            if constexpr (MODE == 0) {
                int tensor = n >> 10, hh = (n >> 6) & 15, d = n & 63;
                u16* dst = tensor == 0 ? o0 : (tensor == 1 ? o1 : o2);
#pragma unroll
                for (int r = 0; r < 4; r++) {
                    int m = m0 + r;
                    int bb = m >> 11, tt = m & 2047;
                    dst[(((size_t)(bb * Hc + hh) * Tc + tt) << 6) + d] = f2bf(acc[i][j][r]);
                }
            } else if constexpr (MODE == 1) {
                float bv = bias[n];
#pragma unroll
                for (int r = 0; r < 4; r++) {
                    int m = m0 + r;
                    o0[(size_t)m * N + n] = f2bf(fmaxf(acc[i][j][r] + bv, 0.f));
                }
            } else {
                float bv = bias[n];
#pragma unroll
                for (int r = 0; r < 4; r++) {
                    int m = m0 + r;
                    of[(size_t)m * N + n] = acc[i][j][r] + bv + res[(size_t)m * N + n];
                }
            }
        }
    }
}

// ---------------- causal flash attention, paired q-blocks for uniform work
// Each block: q-blocks qb and 15-qb (2(qb+1) + 2(16-qb) = 34 KV-tiles, uniform).
// K/V staged once (larger range covers smaller). In-register P redistribution.
__global__ __launch_bounds__(256, 2) void attn_kernel(const u16* __restrict__ q, const u16* __restrict__ k,
                                                      const u16* __restrict__ vt, u16* __restrict__ att) {
    __shared__ u16 Ks[2][64 * 64];
    __shared__ u16 Vs[2][64 * 64];
    int orig = blockIdx.x;
    int swz = (orig & 7) * 128 + (orig >> 3);  // XCD-chunk: XCD x -> bh in [x*16, x*16+16)
    int bh = swz >> 3;
    int qb = swz & 7;
    int bb = bh >> 4, hh = bh & 15;
    int q0a = qb * 128, q0b = (15 - qb) * 128;
    int tid = threadIdx.x;
    int w = tid >> 6, l = tid & 63;
    int q16 = l & 15, g = l >> 4;
    int hig = (g >> 1) & 1;
    int alane0 = ((g & 1) * 2) * 16 + q16;
    int alane1 = alane0 + 16;

    const u16* Q  = q  + (size_t)bh * Tc * DHc;
    const u16* Kp = k  + (size_t)bh * Tc * DHc;
    const u16* Vt = vt + (size_t)bh * DHc * Tc;

    int qwa = q0a + w * 32, qwb = q0b + w * 32;

    s16x8 qfa[2][2], qfb[2][2];
#pragma unroll
    for (int mf = 0; mf < 2; mf++)
#pragma unroll
        for (int c = 0; c < 2; c++) {
            qfa[mf][c] = *(const s16x8*)(Q + (size_t)(qwa + mf * 16 + q16) * DHc + c * 32 + g * 8);
            qfb[mf][c] = *(const s16x8*)(Q + (size_t)(qwb + mf * 16 + q16) * DHc + c * 32 + g * 8);
        }

    f32x4 Ofa[4][2], Ofb[4][2];
#pragma unroll
    for (int i = 0; i < 4; i++)
#pragma unroll
        for (int j = 0; j < 2; j++) { Ofa[i][j] = {0.f, 0.f, 0.f, 0.f}; Ofb[i][j] = {0.f, 0.f, 0.f, 0.f}; }
    float mra[2] = {-1e30f, -1e30f}, lra[2] = {0.f, 0.f};
    float mrb[2] = {-1e30f, -1e30f}, lrb[2] = {0.f, 0.f};
    const float scale2 = 0.03125f * 1.44269504f;  // E^-0.5 * log2(e)

    int ri = tid >> 3, sl = tid & 7;
    auto stage = [&](int t, int bufi) {
        int s0 = t * 64;
        gload16(Kp + (size_t)(s0 + ri) * DHc + ((sl ^ (ri & 7)) << 3),      &Ks[bufi][w * 512]);
        gload16(Kp + (size_t)(s0 + ri + 32) * DHc + ((sl ^ (ri & 7)) << 3), &Ks[bufi][2048 + w * 512]);
        gload16(Vt + (size_t)ri * Tc + s0 + ((sl ^ (ri & 7)) << 3),         &Vs[bufi][w * 512]);
        gload16(Vt + (size_t)(ri + 32) * Tc + s0 + ((sl ^ (ri & 7)) << 3),  &Vs[bufi][2048 + w * 512]);
    };

    auto process = [&](f32x4 (&Of)[4][2], float (&mrun)[2], float (&lrun)[2],
                       const s16x8 (&qf)[2][2], int qw, const u16* Ksb, const u16* Vsb, int s0) {
        s16x8 kf[4][2];
#pragma unroll
        for (int sf = 0; sf < 4; sf++)
#pragma unroll
            for (int c = 0; c < 2; c++)
                kf[sf][c] = *(const s16x8*)(Ksb + (sf * 16 + q16) * 64 + (((c * 4 + g) ^ (q16 & 7)) << 3));

        f32x4 sacc[4][2];
#pragma unroll
        for (int sf = 0; sf < 4; sf++)
#pragma unroll
            for (int j = 0; j < 2; j++) sacc[sf][j] = {0.f, 0.f, 0.f, 0.f};
        __builtin_amdgcn_s_setprio(1);
#pragma unroll
        for (int sf = 0; sf < 4; sf++)
#pragma unroll
            for (int j = 0; j < 2; j++)
#pragma unroll
                for (int c = 0; c < 2; c++)
                    sacc[sf][j] = __builtin_amdgcn_mfma_f32_16x16x32_bf16(kf[sf][c], qf[j][c], sacc[sf][j], 0, 0, 0);
        __builtin_amdgcn_s_setprio(0);

        uint32_t paq[2][2][4];
#pragma unroll
        for (int qfi = 0; qfi < 2; qfi++) {
            int qi = qw + qfi * 16 + q16;
            float tmax = -1e30f;
            bool diag = (s0 + 64 > qw + qfi * 16);
#pragma unroll
            for (int sf = 0; sf < 4; sf++)
#pragma unroll
                for (int r = 0; r < 4; r++) {
                    float val = sacc[sf][qfi][r] * scale2;
                    if (diag) {
                        int s = s0 + sf * 16 + g * 4 + r;
                        if (s > qi) val = -1e30f;
                    }
                    sacc[sf][qfi][r] = val;
                    tmax = fmaxf(tmax, val);
                }
            // defer-max: predicate exact on unreduced per-lane maxes
            if (!__all(tmax <= mrun[qfi] + 8.f)) {
                tmax = fmaxf(tmax, __shfl_xor(tmax, 16));
                tmax = fmaxf(tmax, __shfl_xor(tmax, 32));
                float mnew = fmaxf(mrun[qfi], tmax);
                float alpha = exp2f(mrun[qfi] - mnew);
                mrun[qfi] = mnew;
                lrun[qfi] *= alpha;
#pragma unroll
                for (int df = 0; df < 4; df++) {
                    Of[df][qfi][0] *= alpha; Of[df][qfi][1] *= alpha;
                    Of[df][qfi][2] *= alpha; Of[df][qfi][3] *= alpha;
                }
            }
            float m2 = mrun[qfi];
            float psum = 0.f;
            uint32_t Dk[4][2];
#pragma unroll
            for (int sf = 0; sf < 4; sf++) {
                float p0 = exp2f(sacc[sf][qfi][0] - m2);
                float p1 = exp2f(sacc[sf][qfi][1] - m2);
                float p2 = exp2f(sacc[sf][qfi][2] - m2);
                float p3 = exp2f(sacc[sf][qfi][3] - m2);
                psum += (p0 + p1) + (p2 + p3);
                Dk[sf][0] = cvtpk_bf16(p0, p1);
                Dk[sf][1] = cvtpk_bf16(p2, p3);
            }
            psum += __shfl_xor(psum, 16);
            psum += __shfl_xor(psum, 32);
            lrun[qfi] += psum;
#pragma unroll
            for (int c = 0; c < 2; c++)
#pragma unroll
                for (int kk = 0; kk < 2; kk++) {
                    int rlo0 = __shfl((int)Dk[c * 2][kk], alane0);
                    int rhi0 = __shfl((int)Dk[c * 2 + 1][kk], alane0);
                    paq[qfi][c][kk] = hig ? rhi0 : rlo0;
                    int rlo1 = __shfl((int)Dk[c * 2][kk], alane1);
                    int rhi1 = __shfl((int)Dk[c * 2 + 1][kk], alane1);
                    paq[qfi][c][2 + kk] = hig ? rhi1 : rlo1;
                }
        }

#pragma unroll
        for (int c = 0; c < 2; c++) {
            s16x8 vf[4];
#pragma unroll
            for (int df = 0; df < 4; df++)
                vf[df] = *(const s16x8*)(Vsb + (df * 16 + q16) * 64 + (((c * 4 + g) ^ (q16 & 7)) << 3));
            __builtin_amdgcn_s_setprio(1);
#pragma unroll
            for (int qfi = 0; qfi < 2; qfi++) {
                s16x8 pb;
                memcpy(&pb, &paq[qfi][c][0], 16);
#pragma unroll
                for (int df = 0; df < 4; df++)
                    Of[df][qfi] = __builtin_amdgcn_mfma_f32_16x16x32_bf16(vf[df], pb, Of[df][qfi], 0, 0, 0);
            }
            __builtin_amdgcn_s_setprio(0);
        }
    };

    int nt = q0b / 64 + 2;
    stage(0, 0);
    for (int t = 0; t < nt; ++t) {
        int cur = t & 1;
        if (t + 1 < nt) {
            stage(t + 1, cur ^ 1);
            asm volatile("s_waitcnt vmcnt(4)" ::: "memory");
        } else {
            asm volatile("s_waitcnt vmcnt(0)" ::: "memory");
        }
        __syncthreads();
        int s0 = t * 64;
        const u16* Ksb = &Ks[cur][0];
        const u16* Vsb = &Vs[cur][0];
        if (s0 < qwa + 32) process(Ofa, mra, lra, qfa, qwa, Ksb, Vsb, s0);
        if (s0 < qwb + 32) process(Ofb, mrb, lrb, qfb, qwb, Ksb, Vsb, s0);
        __syncthreads();
    }

    auto store_o = [&](f32x4 (&Of)[4][2], float (&lrun)[2], int qw) {
#pragma unroll
        for (int qfi = 0; qfi < 2; qfi++) {
            float inv = 1.f / lrun[qfi];
            int tq = qw + qfi * 16 + q16;
#pragma unroll
            for (int df = 0; df < 4; df++) {
                u16x4 o;
                o[0] = f2bf(Of[df][qfi][0] * inv);
                o[1] = f2bf(Of[df][qfi][1] * inv);
                o[2] = f2bf(Of[df][qfi][2] * inv);
                o[3] = f2bf(Of[df][qfi][3] * inv);
                *(u16x4*)(att + ((size_t)(bb * Tc + tq)) * Ec + hh * 64 + df * 16 + g * 4) = o;
            }
        }
    };
    store_o(Ofa, lra, qwa);
    store_o(Ofb, lrb, qwb);
}

extern "C" void kernel_launch(void* const* d_in, const int* in_sizes, int n_in,
                              void* d_out, int out_size, void* d_ws, size_t ws_size,
                              hipStream_t stream) {
    (void)in_sizes; (void)n_in; (void)out_size; (void)ws_size;
    const float* x    = (const float*)d_in[0];
    const float* ln1g = (const float*)d_in[1];
    const float* ln1b = (const float*)d_in[2];
    const float* Wq   = (const float*)d_in[3];
    const float* Wk   = (const float*)d_in[4];
    const float* Wv   = (const float*)d_in[5];
    const float* Wp   = (const float*)d_in[6];
    const float* bp   = (const float*)d_in[7];
    const float* ln2g = (const float*)d_in[8];
    const float* ln2b = (const float*)d_in[9];
    const float* W1   = (const float*)d_in[10];
    const float* b1   = (const float*)d_in[11];
    const float* W2   = (const float*)d_in[12];
    const float* b2   = (const float*)d_in[13];
    float* out = (float*)d_out;
    char* ws = (char*)d_ws;

    u16*  wqkvt = (u16*)(ws + 0);           // [3072][1024] bf16
    u16*  wpt   = (u16*)(ws + 6291456);     // [1024][1024]
    u16*  w1t   = (u16*)(ws + 8388608);     // [4096][1024]
    u16*  w2t   = (u16*)(ws + 16777216);    // [1024][4096]
    u16*  h     = (u16*)(ws + 25165824);    // [8192][1024] bf16 (reused as att)
    u16*  att   = h;
    u16*  qb    = (u16*)(ws + 41943040);    // [B,H,T,64] (reused as h2)
    u16*  h2    = qb;
    u16*  kb    = (u16*)(ws + 58720256);
    u16*  vb    = (u16*)(ws + 75497472);    // [B,H,T,64]
    u16*  vtb   = (u16*)(ws + 92274688);    // [B,H,64,T]
    float* x2   = (float*)(ws + 109051904); // [8192][1024] f32
    u16*  ff1   = (u16*)(ws + 142606336);   // [8192][4096] bf16

    dim3 tb(32, 8);
    transpose_conv<float><<<dim3(2, 32, 16), tb, 0, stream>>>(Wq, wqkvt,            1024, 64);
    transpose_conv<float><<<dim3(2, 32, 16), tb, 0, stream>>>(Wk, wqkvt + 1048576,  1024, 64);
    transpose_conv<float><<<dim3(2, 32, 16), tb, 0, stream>>>(Wv, wqkvt + 2097152,  1024, 64);
    transpose_conv<float><<<dim3(32, 32, 1), tb, 0, stream>>>(Wp, wpt, 1024, 1024);
    transpose_conv<float><<<dim3(128, 32, 1), tb, 0, stream>>>(W1, w1t, 1024, 4096);
    transpose_conv<float><<<dim3(32, 128, 1), tb, 0, stream>>>(W2, w2t, 4096, 1024);

    ln_kernel<<<8192, 256, 0, stream>>>(x, ln1g, ln1b, h);

    gemm_kernel<0><<<dim3(24, 64), 256, 0, stream>>>(h, wqkvt, 1024, 3072, qb, kb, vb, nullptr, nullptr, nullptr);

    transpose_conv<u16><<<dim3(2, 64, 64), tb, 0, stream>>>(vb, vtb, 2048, 64);

    attn_kernel<<<1024, 256, 0, stream>>>(qb, kb, vtb, att);

    gemm_kernel<2><<<dim3(8, 64), 256, 0, stream>>>(att, wpt, 1024, 1024, nullptr, nullptr, nullptr, x2, bp, x);

    ln_kernel<<<8192, 256, 0, stream>>>(x2, ln2g, ln2b, h2);

    gemm_kernel<1><<<dim3(32, 64), 256, 0, stream>>>(h2, w1t, 1024, 4096, ff1, nullptr, nullptr, nullptr, b1, nullptr);

    gemm_kernel<2><<<dim3(8, 64), 256, 0, stream>>>(ff1, w2t, 4096, 1024, nullptr, nullptr, nullptr, out, b2, x2);
}

// Round 6
// 603.301 us; speedup vs baseline: 1.1231x; 1.1231x over previous
//
#include <hip/hip_runtime.h>
#include <stdint.h>

#define DEV __device__ __forceinline__

typedef unsigned short u16;
typedef short s16x8 __attribute__((ext_vector_type(8)));
typedef u16 u16x4 __attribute__((ext_vector_type(4)));
typedef float f32x4 __attribute__((ext_vector_type(4)));

constexpr int Bc = 4, Tc = 2048, Ec = 1024, Hc = 16, DHc = 64, FFc = 4096;

DEV u16 f2bf(float f) {
    union { float f; uint32_t u; } v; v.f = f;
    uint32_t r = v.u + 0x7fffu + ((v.u >> 16) & 1u);
    return (u16)(r >> 16);
}
DEV float bf2f(u16 u) {
    union { uint32_t u; float f; } v; v.u = ((uint32_t)u) << 16;
    return v.f;
}
DEV uint32_t cvtpk_bf16(float lo, float hi) {
    uint32_t r;
    asm("v_cvt_pk_bf16_f32 %0, %1, %2" : "=v"(r) : "v"(lo), "v"(hi));
    return r;
}

// async global->LDS, 16B per lane, dest = wave-uniform base + lane*16
DEV void gload16(const void* g, void* l) {
    __builtin_amdgcn_global_load_lds((const __attribute__((address_space(1))) void*)g,
                                     (__attribute__((address_space(3))) void*)l, 16, 0, 0);
}

// ---------------- transpose + convert:  in [R][C] (f32 or bf16) -> out bf16 [C][R]
template <typename TIN>
__global__ __launch_bounds__(256) void transpose_conv(const TIN* __restrict__ in,
                                                      u16* __restrict__ out, int R, int C) {
    __shared__ float tile[32][33];
    int bz = blockIdx.z;
    in  += (size_t)bz * R * C;
    out += (size_t)bz * R * C;
    int c0 = blockIdx.x * 32, r0 = blockIdx.y * 32;
    int tx = threadIdx.x, ty = threadIdx.y;  // 32 x 8
#pragma unroll
    for (int i = 0; i < 4; i++) {
        int r = ty + 8 * i;
        float v;
        if constexpr (sizeof(TIN) == 4) v = ((const float*)in)[(size_t)(r0 + r) * C + c0 + tx];
        else                            v = bf2f(((const u16*)in)[(size_t)(r0 + r) * C + c0 + tx]);
        tile[r][tx] = v;
    }
    __syncthreads();
#pragma unroll
    for (int i = 0; i < 4; i++) {
        int c = ty + 8 * i;
        out[(size_t)(c0 + c) * R + r0 + tx] = f2bf(tile[tx][c]);
    }
}

// ---------------- LayerNorm (row of 1024 f32) -> bf16
__global__ __launch_bounds__(256) void ln_kernel(const float* __restrict__ x, const float* __restrict__ g,
                                                 const float* __restrict__ b, u16* __restrict__ out) {
    int row = blockIdx.x;
    const float4* xr = (const float4*)(x + (size_t)row * Ec);
    int t = threadIdx.x;
    float4 v = xr[t];
    float s = v.x + v.y + v.z + v.w;
    float ss = v.x * v.x + v.y * v.y + v.z * v.z + v.w * v.w;
#pragma unroll
    for (int off = 32; off > 0; off >>= 1) { s += __shfl_xor(s, off); ss += __shfl_xor(ss, off); }
    __shared__ float red[8];
    int wid = t >> 6;
    if ((t & 63) == 0) { red[wid] = s; red[4 + wid] = ss; }
    __syncthreads();
    s = red[0] + red[1] + red[2] + red[3];
    ss = red[4] + red[5] + red[6] + red[7];
    float mu = s * (1.f / Ec);
    float rs = rsqrtf(ss * (1.f / Ec) - mu * mu + 1e-5f);
    float4 gv = ((const float4*)g)[t], bv = ((const float4*)b)[t];
    u16x4 o;
    o[0] = f2bf((v.x - mu) * rs * gv.x + bv.x);
    o[1] = f2bf((v.y - mu) * rs * gv.y + bv.y);
    o[2] = f2bf((v.z - mu) * rs * gv.z + bv.z);
    o[3] = f2bf((v.w - mu) * rs * gv.w + bv.w);
    *(u16x4*)(out + (size_t)row * Ec + t * 4) = o;
}

// ---------------- GEMM: C[M,N] = A[M,K](bf16) * Bt[N,K](bf16)^T, m97 structure
// XCD-chunk swizzled block mapping (nwg % 8 == 0 for all our grids).
// MODE 0: qkv split-store bf16: Q,K,V -> [B,H,T,64] (coalesced)
// MODE 1: bf16 out = relu(acc + bias)
// MODE 2: f32 out = acc + bias + res
template <int MODE>
__global__ __launch_bounds__(256) void gemm_kernel(const u16* __restrict__ A, const u16* __restrict__ Bt,
                                                   int K, int N,
                                                   u16* __restrict__ o0, u16* __restrict__ o1, u16* __restrict__ o2,
                                                   float* __restrict__ of, const float* __restrict__ bias,
                                                   const float* __restrict__ res) {
    __shared__ u16 As[128 * 32];
    __shared__ u16 Bs[128 * 32];
    int lin = blockIdx.y * gridDim.x + blockIdx.x;
    int cpx = (gridDim.x * gridDim.y) >> 3;
    int swz = (lin & 7) * cpx + (lin >> 3);
    int tm = (swz / gridDim.x) * 128, tn = (swz % gridDim.x) * 128;
    int tid = threadIdx.x;
    int w = tid >> 6, l = tid & 63;
    int wm = w >> 1, wn = w & 1;
    int q16 = l & 15, g = l >> 4;

    f32x4 acc[4][4];
#pragma unroll
    for (int i = 0; i < 4; i++)
#pragma unroll
        for (int j = 0; j < 4; j++) acc[i][j] = {0.f, 0.f, 0.f, 0.f};

    const u16* Aw0 = A + (size_t)(tm + w * 32 + (l >> 2)) * K + (l & 3) * 8;
    const u16* Aw1 = Aw0 + (size_t)16 * K;
    const u16* Bw0 = Bt + (size_t)(tn + w * 32 + (l >> 2)) * K + (l & 3) * 8;
    const u16* Bw1 = Bw0 + (size_t)16 * K;
    u16* Asw = As + (w * 32) * 32;
    u16* Bsw = Bs + (w * 32) * 32;

    for (int k0 = 0; k0 < K; k0 += 32) {
        gload16(Aw0 + k0, Asw);
        gload16(Aw1 + k0, Asw + 16 * 32);
        gload16(Bw0 + k0, Bsw);
        gload16(Bw1 + k0, Bsw + 16 * 32);
        asm volatile("s_waitcnt vmcnt(0)" ::: "memory");
        __syncthreads();
        s16x8 af[4], bfr[4];
#pragma unroll
        for (int i = 0; i < 4; i++) {
            af[i]  = *(const s16x8*)(As + (wm * 64 + i * 16 + q16) * 32 + g * 8);
            bfr[i] = *(const s16x8*)(Bs + (wn * 64 + i * 16 + q16) * 32 + g * 8);
        }
#pragma unroll
        for (int i = 0; i < 4; i++)
#pragma unroll
            for (int j = 0; j < 4; j++)
                acc[i][j] = __builtin_amdgcn_mfma_f32_16x16x32_bf16(af[i], bfr[j], acc[i][j], 0, 0, 0);
        __syncthreads();
    }

#pragma unroll
    for (int i = 0; i < 4; i++) {
        int m0 = tm + wm * 64 + i * 16 + g * 4;
#pragma unroll
        for (int j = 0; j < 4; j++) {
            int n = tn + wn * 64 + j * 16 + q16;
            if constexpr (MODE == 0) {
                int tensor = n >> 10, hh = (n >> 6) & 15, d = n & 63;
                u16* dst = tensor == 0 ? o0 : (tensor == 1 ? o1 : o2);
#pragma unroll
                for (int r = 0; r < 4; r++) {
                    int m = m0 + r;
                    int bb = m >> 11, tt = m & 2047;
                    dst[(((size_t)(bb * Hc + hh) * Tc + tt) << 6) + d] = f2bf(acc[i][j][r]);
                }
            } else if constexpr (MODE == 1) {
                float bv = bias[n];
#pragma unroll
                for (int r = 0; r < 4; r++) {
                    int m = m0 + r;
                    o0[(size_t)m * N + n] = f2bf(fmaxf(acc[i][j][r] + bv, 0.f));
                }
            } else {
                float bv = bias[n];
#pragma unroll
                for (int r = 0; r < 4; r++) {
                    int m = m0 + r;
                    of[(size_t)m * N + n] = acc[i][j][r] + bv + res[(size_t)m * N + n];
                }
            }
        }
    }
}

// ---------------- causal flash attention (unpaired, R2 structure + spill headroom)
// q,k: [B,H,T,64] bf16 ; vt: [B,H,64,T] bf16 ; att out: [B,T,E] bf16
// K/V double-buffered in LDS (XOR-swizzled via pre-swizzled global source),
// counted vmcnt(4); softmax in-register via swapped QK^T; P redistributed by shuffles.
__global__ __launch_bounds__(256, 3) void attn_kernel(const u16* __restrict__ q, const u16* __restrict__ k,
                                                      const u16* __restrict__ vt, u16* __restrict__ att) {
    __shared__ u16 Ks[2][64 * 64];
    __shared__ u16 Vs[2][64 * 64];
    int orig = blockIdx.x;
    int swz = (orig & 7) * 128 + (orig >> 3);  // XCD-chunk: XCD x -> bh in [x*16, x*16+16)
    int bh = swz >> 4;
    int q0 = (15 - (swz & 15)) * 128;          // heavy q-blocks first
    int bb = bh >> 4, hh = bh & 15;
    int tid = threadIdx.x;
    int w = tid >> 6, l = tid & 63;
    int q16 = l & 15, g = l >> 4;
    int hig = (g >> 1) & 1;
    int alane0 = ((g & 1) * 2) * 16 + q16;
    int alane1 = alane0 + 16;

    const u16* Q  = q  + (size_t)bh * Tc * DHc;
    const u16* Kp = k  + (size_t)bh * Tc * DHc;
    const u16* Vt = vt + (size_t)bh * DHc * Tc;

    int qw = q0 + w * 32;

    s16x8 qf[2][2];
#pragma unroll
    for (int mf = 0; mf < 2; mf++)
#pragma unroll
        for (int c = 0; c < 2; c++)
            qf[mf][c] = *(const s16x8*)(Q + (size_t)(qw + mf * 16 + q16) * DHc + c * 32 + g * 8);

    f32x4 Of[4][2];
#pragma unroll
    for (int i = 0; i < 4; i++)
#pragma unroll
        for (int j = 0; j < 2; j++) Of[i][j] = {0.f, 0.f, 0.f, 0.f};
    float mrun[2] = {-1e30f, -1e30f};
    float lrun[2] = {0.f, 0.f};
    const float scale2 = 0.03125f * 1.44269504f;  // E^-0.5 * log2(e)

    int ri = tid >> 3, sl = tid & 7;
    auto stage = [&](int t, int bufi) {
        int s0 = t * 64;
        gload16(Kp + (size_t)(s0 + ri) * DHc + ((sl ^ (ri & 7)) << 3),      &Ks[bufi][w * 512]);
        gload16(Kp + (size_t)(s0 + ri + 32) * DHc + ((sl ^ (ri & 7)) << 3), &Ks[bufi][2048 + w * 512]);
        gload16(Vt + (size_t)ri * Tc + s0 + ((sl ^ (ri & 7)) << 3),         &Vs[bufi][w * 512]);
        gload16(Vt + (size_t)(ri + 32) * Tc + s0 + ((sl ^ (ri & 7)) << 3),  &Vs[bufi][2048 + w * 512]);
    };

    int nt = q0 / 64 + 2;
    stage(0, 0);
    for (int t = 0; t < nt; ++t) {
        int cur = t & 1;
        if (t + 1 < nt) {
            stage(t + 1, cur ^ 1);
            asm volatile("s_waitcnt vmcnt(4)" ::: "memory");
        } else {
            asm volatile("s_waitcnt vmcnt(0)" ::: "memory");
        }
        __syncthreads();
        int s0 = t * 64;
        if (s0 < qw + 32) {
            const u16* Ksb = &Ks[cur][0];
            const u16* Vsb = &Vs[cur][0];
            s16x8 kf[4][2];
#pragma unroll
            for (int sf = 0; sf < 4; sf++)
#pragma unroll
                for (int c = 0; c < 2; c++)
                    kf[sf][c] = *(const s16x8*)(Ksb + (sf * 16 + q16) * 64 + (((c * 4 + g) ^ (q16 & 7)) << 3));

            f32x4 sacc[4][2];
#pragma unroll
            for (int sf = 0; sf < 4; sf++)
#pragma unroll
                for (int j = 0; j < 2; j++) sacc[sf][j] = {0.f, 0.f, 0.f, 0.f};
            __builtin_amdgcn_s_setprio(1);
#pragma unroll
            for (int sf = 0; sf < 4; sf++)
#pragma unroll
                for (int j = 0; j < 2; j++)
#pragma unroll
                    for (int c = 0; c < 2; c++)
                        sacc[sf][j] = __builtin_amdgcn_mfma_f32_16x16x32_bf16(kf[sf][c], qf[j][c], sacc[sf][j], 0, 0, 0);
            __builtin_amdgcn_s_setprio(0);

            uint32_t paq[2][2][4];
#pragma unroll
            for (int qfi = 0; qfi < 2; qfi++) {
                int qi = qw + qfi * 16 + q16;
                float tmax = -1e30f;
                bool diag = (s0 + 64 > qw + qfi * 16);
#pragma unroll
                for (int sf = 0; sf < 4; sf++)
#pragma unroll
                    for (int r = 0; r < 4; r++) {
                        float val = sacc[sf][qfi][r] * scale2;
                        if (diag) {
                            int s = s0 + sf * 16 + g * 4 + r;
                            if (s > qi) val = -1e30f;
                        }
                        sacc[sf][qfi][r] = val;
                        tmax = fmaxf(tmax, val);
                    }
                // defer-max: predicate exact on unreduced per-lane maxes
                if (!__all(tmax <= mrun[qfi] + 8.f)) {
                    tmax = fmaxf(tmax, __shfl_xor(tmax, 16));
                    tmax = fmaxf(tmax, __shfl_xor(tmax, 32));
                    float mnew = fmaxf(mrun[qfi], tmax);
                    float alpha = exp2f(mrun[qfi] - mnew);
                    mrun[qfi] = mnew;
                    lrun[qfi] *= alpha;
#pragma unroll
                    for (int df = 0; df < 4; df++) {
                        Of[df][qfi][0] *= alpha; Of[df][qfi][1] *= alpha;
                        Of[df][qfi][2] *= alpha; Of[df][qfi][3] *= alpha;
                    }
                }
                float m2 = mrun[qfi];
                float psum = 0.f;
                uint32_t Dk[4][2];
#pragma unroll
                for (int sf = 0; sf < 4; sf++) {
                    float p0 = exp2f(sacc[sf][qfi][0] - m2);
                    float p1 = exp2f(sacc[sf][qfi][1] - m2);
                    float p2 = exp2f(sacc[sf][qfi][2] - m2);
                    float p3 = exp2f(sacc[sf][qfi][3] - m2);
                    psum += (p0 + p1) + (p2 + p3);
                    Dk[sf][0] = cvtpk_bf16(p0, p1);
                    Dk[sf][1] = cvtpk_bf16(p2, p3);
                }
                psum += __shfl_xor(psum, 16);
                psum += __shfl_xor(psum, 32);
                lrun[qfi] += psum;
                // redistribute P^T into MFMA B-frag layout: pure g-group permutation, q16 lane-local
#pragma unroll
                for (int c = 0; c < 2; c++)
#pragma unroll
                    for (int kk = 0; kk < 2; kk++) {
                        int rlo0 = __shfl((int)Dk[c * 2][kk], alane0);
                        int rhi0 = __shfl((int)Dk[c * 2 + 1][kk], alane0);
                        paq[qfi][c][kk] = hig ? rhi0 : rlo0;
                        int rlo1 = __shfl((int)Dk[c * 2][kk], alane1);
                        int rhi1 = __shfl((int)Dk[c * 2 + 1][kk], alane1);
                        paq[qfi][c][2 + kk] = hig ? rhi1 : rlo1;
                    }
            }

            // PV: attT[d][q] += V^T[d][s'] * P^T[s'][q]
#pragma unroll
            for (int c = 0; c < 2; c++) {
                s16x8 vf[4];
#pragma unroll
                for (int df = 0; df < 4; df++)
                    vf[df] = *(const s16x8*)(Vsb + (df * 16 + q16) * 64 + (((c * 4 + g) ^ (q16 & 7)) << 3));
                __builtin_amdgcn_s_setprio(1);
#pragma unroll
                for (int qfi = 0; qfi < 2; qfi++) {
                    s16x8 pb;
                    memcpy(&pb, &paq[qfi][c][0], 16);
#pragma unroll
                    for (int df = 0; df < 4; df++)
                        Of[df][qfi] = __builtin_amdgcn_mfma_f32_16x16x32_bf16(vf[df], pb, Of[df][qfi], 0, 0, 0);
                }
                __builtin_amdgcn_s_setprio(0);
            }
        }
        __syncthreads();
    }

#pragma unroll
    for (int qfi = 0; qfi < 2; qfi++) {
        float inv = 1.f / lrun[qfi];
        int tq = qw + qfi * 16 + q16;
#pragma unroll
        for (int df = 0; df < 4; df++) {
            u16x4 o;
            o[0] = f2bf(Of[df][qfi][0] * inv);
            o[1] = f2bf(Of[df][qfi][1] * inv);
            o[2] = f2bf(Of[df][qfi][2] * inv);
            o[3] = f2bf(Of[df][qfi][3] * inv);
            *(u16x4*)(att + ((size_t)(bb * Tc + tq)) * Ec + hh * 64 + df * 16 + g * 4) = o;
        }
    }
}

extern "C" void kernel_launch(void* const* d_in, const int* in_sizes, int n_in,
                              void* d_out, int out_size, void* d_ws, size_t ws_size,
                              hipStream_t stream) {
    (void)in_sizes; (void)n_in; (void)out_size; (void)ws_size;
    const float* x    = (const float*)d_in[0];
    const float* ln1g = (const float*)d_in[1];
    const float* ln1b = (const float*)d_in[2];
    const float* Wq   = (const float*)d_in[3];
    const float* Wk   = (const float*)d_in[4];
    const float* Wv   = (const float*)d_in[5];
    const float* Wp   = (const float*)d_in[6];
    const float* bp   = (const float*)d_in[7];
    const float* ln2g = (const float*)d_in[8];
    const float* ln2b = (const float*)d_in[9];
    const float* W1   = (const float*)d_in[10];
    const float* b1   = (const float*)d_in[11];
    const float* W2   = (const float*)d_in[12];
    const float* b2   = (const float*)d_in[13];
    float* out = (float*)d_out;
    char* ws = (char*)d_ws;

    u16*  wqkvt = (u16*)(ws + 0);           // [3072][1024] bf16
    u16*  wpt   = (u16*)(ws + 6291456);     // [1024][1024]
    u16*  w1t   = (u16*)(ws + 8388608);     // [4096][1024]
    u16*  w2t   = (u16*)(ws + 16777216);    // [1024][4096]
    u16*  h     = (u16*)(ws + 25165824);    // [8192][1024] bf16 (reused as att)
    u16*  att   = h;
    u16*  qb    = (u16*)(ws + 41943040);    // [B,H,T,64] (reused as h2)
    u16*  h2    = qb;
    u16*  kb    = (u16*)(ws + 58720256);
    u16*  vb    = (u16*)(ws + 75497472);    // [B,H,T,64]
    u16*  vtb   = (u16*)(ws + 92274688);    // [B,H,64,T]
    float* x2   = (float*)(ws + 109051904); // [8192][1024] f32
    u16*  ff1   = (u16*)(ws + 142606336);   // [8192][4096] bf16

    dim3 tb(32, 8);
    transpose_conv<float><<<dim3(2, 32, 16), tb, 0, stream>>>(Wq, wqkvt,            1024, 64);
    transpose_conv<float><<<dim3(2, 32, 16), tb, 0, stream>>>(Wk, wqkvt + 1048576,  1024, 64);
    transpose_conv<float><<<dim3(2, 32, 16), tb, 0, stream>>>(Wv, wqkvt + 2097152,  1024, 64);
    transpose_conv<float><<<dim3(32, 32, 1), tb, 0, stream>>>(Wp, wpt, 1024, 1024);
    transpose_conv<float><<<dim3(128, 32, 1), tb, 0, stream>>>(W1, w1t, 1024, 4096);
    transpose_conv<float><<<dim3(32, 128, 1), tb, 0, stream>>>(W2, w2t, 4096, 1024);

    ln_kernel<<<8192, 256, 0, stream>>>(x, ln1g, ln1b, h);

    gemm_kernel<0><<<dim3(24, 64), 256, 0, stream>>>(h, wqkvt, 1024, 3072, qb, kb, vb, nullptr, nullptr, nullptr);

    transpose_conv<u16><<<dim3(2, 64, 64), tb, 0, stream>>>(vb, vtb, 2048, 64);

    attn_kernel<<<1024, 256, 0, stream>>>(qb, kb, vtb, att);

    gemm_kernel<2><<<dim3(8, 64), 256, 0, stream>>>(att, wpt, 1024, 1024, nullptr, nullptr, nullptr, x2, bp, x);

    ln_kernel<<<8192, 256, 0, stream>>>(x2, ln2g, ln2b, h2);

    gemm_kernel<1><<<dim3(32, 64), 256, 0, stream>>>(h2, w1t, 1024, 4096, ff1, nullptr, nullptr, nullptr, b1, nullptr);

    gemm_kernel<2><<<dim3(8, 64), 256, 0, stream>>>(ff1, w2t, 4096, 1024, nullptr, nullptr, nullptr, out, b2, x2);
}